// Round 2
// baseline (341.923 us; speedup 1.0000x reference)
//
#include <hip/hip_runtime.h>

// ---------------------------------------------------------------------------
// MMoE forward, MI355X/gfx950.  Round 2.
// GEMMs now use a tri-buffered LDS pipeline: ONE raw s_barrier per K-step,
// counted s_waitcnt vmcnt(6) (never 0 in steady state), 256x128 tile, BK=64,
// 8 waves (64x64 per wave), XOR-swizzled LDS (swizzle on global source +
// ds_read; LDS dest linear — both-sides rule).  setprio(1) around MFMA.
// Correctness ledger:
//   * vmcnt retires in order; each wave waits vmcnt(6) BEFORE the barrier,
//     so after the barrier tile t is fully in LDS (all waves' loads landed).
//   * stage(t+2) targets buf[(t-1)%3]; every wave lgkm-completed its reads
//     of that buffer at iter t-1 before reaching this barrier -> no race.
//   * Loop-invariant loads the compiler may hoist/sink only ADD newer vmem
//     ops, making vmcnt(6) stricter, never looser.
// eo is bf16 now (error adds ~2e-7 at out; margin vs 3.19e-6 kept).
// ---------------------------------------------------------------------------

typedef unsigned short u16;
typedef unsigned int u32;
typedef __attribute__((ext_vector_type(8))) __bf16 bf16x8;
typedef __attribute__((ext_vector_type(4))) float f32x4;
typedef __attribute__((ext_vector_type(4))) unsigned short u16x4;

#define DEVINL __device__ __forceinline__

DEVINL u16 f2bf(float f) {            // float -> bf16 bits, round-nearest-even
  union { float f; u32 u; } x; x.f = f;
  u32 u = x.u;
  return (u16)((u + 0x7fffu + ((u >> 16) & 1u)) >> 16);
}
DEVINL float bf2f(u16 h) {
  union { u32 u; float f; } x; x.u = ((u32)h) << 16;
  return x.f;
}
DEVINL void gload16(const u16* g, u16* l) {   // 16B global -> LDS direct
  __builtin_amdgcn_global_load_lds((const __attribute__((address_space(1))) void*)g,
                                   (__attribute__((address_space(3))) void*)l,
                                   16, 0, 0);
}

// --------------------------- weight transpose ------------------------------
// W [E][K][N] f32 -> WT [E][N][Kpad] bf16, zero-padding K..Kpad.
__global__ __launch_bounds__(256)
void transpose_w_kernel(const float* __restrict__ W, u16* __restrict__ WT,
                        int K, int N, int Kpad)
{
  __shared__ float tbuf[16][65];
  const int e = blockIdx.z;
  const float* We = W + (size_t)e * K * N;
  u16* Wt = WT + (size_t)e * N * Kpad;
  const int k0 = blockIdx.x * 16, n0 = blockIdx.y * 64;
#pragma unroll
  for (int p = 0; p < 4; ++p) {
    const int idx = threadIdx.x + p * 256;
    const int nl = idx & 63, kl = idx >> 6;
    const int gk = k0 + kl;
    tbuf[kl][nl] = (gk < K) ? We[(size_t)gk * N + n0 + nl] : 0.f;
  }
  __syncthreads();
#pragma unroll
  for (int p = 0; p < 4; ++p) {
    const int idx = threadIdx.x + p * 256;
    const int kl = idx & 15, nl = idx >> 4;
    Wt[(size_t)(n0 + nl) * Kpad + k0 + kl] = f2bf(tbuf[kl][nl]);
  }
}

// ------------------------------- gather ------------------------------------
// One wave per row: bf16 expert_in[row][704] (deep 640 | cont 10 | pad 54),
// fp32 softmax gates[row][2][8].  Deep gather uses float4 (16B) loads.
__global__ __launch_bounds__(256)
void gather_kernel(const int* __restrict__ Xd, const float* __restrict__ Xc,
                   const float* __restrict__ lin_emb, const float* __restrict__ deep_emb,
                   const float* __restrict__ gW, const float* __restrict__ gb,
                   u16* __restrict__ ein, float* __restrict__ gates,
                   int rowBase, int Bc)
{
  __shared__ float gi[4][32];
  const int wid = threadIdx.x >> 6, lane = threadIdx.x & 63;
  const int rl = blockIdx.x * 4 + wid;
  const int r = rowBase + rl;
  const int* xd = Xd + (size_t)r * 20;
  u16* er = ein + (size_t)rl * 704;
#pragma unroll
  for (int i = 0; i < 3; ++i) {                 // 20 feat x 8 subchunks = 160
    const int li = i * 64 + lane;
    if (li < 160) {
      const int f = li >> 3, sub = li & 7;
      const int idx = xd[f];
      const float4 v = *(const float4*)&deep_emb[((size_t)f * 100000 + idx) * 32 + sub * 4];
      u16x4 o;
      o.x = f2bf(v.x); o.y = f2bf(v.y); o.z = f2bf(v.z); o.w = f2bf(v.w);
      *(u16x4*)&er[f * 32 + sub * 4] = o;
    }
  }
  if (lane < 10) er[640 + lane] = f2bf(Xc[(size_t)r * 10 + lane]);
  if (lane < 54) er[650 + lane] = 0;
  if (lane < 20) gi[wid][lane] = lin_emb[(size_t)lane * 100000 + xd[lane]];
  if (lane < 10) gi[wid][20 + lane] = Xc[(size_t)r * 10 + lane];
  asm volatile("s_waitcnt lgkmcnt(0)" ::: "memory");
  float logit = 0.f;
  const int t = lane >> 3, ee = lane & 7;
  if (lane < 16) {
    float a = gb[t * 8 + ee];
#pragma unroll
    for (int i = 0; i < 30; ++i) a += gi[wid][i] * gW[(t * 30 + i) * 8 + ee];
    logit = a;
  }
  float mx = logit;
#pragma unroll
  for (int d = 1; d < 8; d <<= 1) mx = fmaxf(mx, __shfl_xor(mx, d));
  float p = expf(logit - mx);
  float sm = p;
#pragma unroll
  for (int d = 1; d < 8; d <<= 1) sm += __shfl_xor(sm, d);
  if (lane < 16) gates[(size_t)rl * 16 + lane] = p / sm;
}

// ------------------------------ grouped GEMM -------------------------------
// C[e] = act(A[e] [M x K] * B[e]^T [N x K] + bias[e]);  K mult of 64, M mult
// of 256, N mult of 128.  grid (N/128, M/256, E), block 512 (8 waves 4Mx2N).
template<bool RELU, typename CT>
__global__ __launch_bounds__(512, 2)
void gemm_kernel(const u16* __restrict__ A, size_t sAe,
                 const u16* __restrict__ Bw, size_t sBe,
                 CT* __restrict__ C, size_t sCe, int ldc,
                 const float* __restrict__ bias, int N, int K)
{
  __shared__ u16 As[3][16384];   // [256][64] bf16 per buf, swizzled
  __shared__ u16 Bs[3][8192];    // [128][64]
  const int e = blockIdx.z;
  const u16* Ae = A + (size_t)e * sAe;
  const u16* Be = Bw + (size_t)e * sBe;
  const int row0 = blockIdx.y * 256;
  const int col0 = blockIdx.x * 128;
  const int tid = threadIdx.x;
  const int lane = tid & 63;
  const int wid = tid >> 6;
  const int wr = wid >> 1, wc = wid & 1;       // 4 wave-rows x 2 wave-cols
  const int KT = K >> 6;

  // Staging: per thread 4 A-loads + 2 B-loads of 16B.  LDS dest is linear
  // (base + tid*16B); the XOR swizzle is applied to the GLOBAL source chunk
  // (ch ^ (row&7)) so the ds_read applies the same involution.
  const int r8 = tid >> 3;                     // 0..63
  const int ch = tid & 7;
  auto stage = [&](int buf, int kt) {
    const int kb = kt << 6;
#pragma unroll
    for (int i = 0; i < 4; ++i) {
      const int rr = i * 64 + r8;
      const int gc = ch ^ (rr & 7);
      gload16(Ae + ((size_t)(row0 + rr) * K + kb + (gc << 3)),
              &As[buf][i * 4096 + tid * 8]);
    }
#pragma unroll
    for (int i = 0; i < 2; ++i) {
      const int rr = i * 64 + r8;
      const int gc = ch ^ (rr & 7);
      gload16(Be + ((size_t)(col0 + rr) * K + kb + (gc << 3)),
              &Bs[buf][i * 4096 + tid * 8]);
    }
  };

  f32x4 acc[4][4];
#pragma unroll
  for (int m = 0; m < 4; ++m)
#pragma unroll
    for (int n = 0; n < 4; ++n) acc[m][n] = {0.f, 0.f, 0.f, 0.f};

  stage(0, 0);
  if (KT > 1) stage(1, 1);

  int cur = 0, nx2 = 2;
  for (int t = 0; t < KT; ++t) {
    if (t + 1 < KT) { asm volatile("s_waitcnt vmcnt(6)" ::: "memory"); }
    else            { asm volatile("s_waitcnt vmcnt(0)" ::: "memory"); }
    __builtin_amdgcn_s_barrier();
    asm volatile("" ::: "memory");             // no LDS ops cross the barrier
    __builtin_amdgcn_sched_barrier(0);
    if (t + 2 < KT) stage(nx2, t + 2);         // overwrites buf freed at t-1
    const u16* as = &As[cur][0];
    const u16* bs = &Bs[cur][0];
#pragma unroll
    for (int half = 0; half < 2; ++half) {     // k = 0..31, 32..63
      const int kp = half * 4 + (lane >> 4);
      bf16x8 af[4], bfr[4];
#pragma unroll
      for (int m = 0; m < 4; ++m) {
        const int rw = wr * 64 + m * 16 + (lane & 15);
        af[m] = *(const bf16x8*)&as[rw * 64 + ((kp ^ (rw & 7)) << 3)];
      }
#pragma unroll
      for (int n = 0; n < 4; ++n) {
        const int rw = wc * 64 + n * 16 + (lane & 15);
        bfr[n] = *(const bf16x8*)&bs[rw * 64 + ((kp ^ (rw & 7)) << 3)];
      }
      __builtin_amdgcn_s_setprio(1);
#pragma unroll
      for (int m = 0; m < 4; ++m)
#pragma unroll
        for (int n = 0; n < 4; ++n)
          acc[m][n] = __builtin_amdgcn_mfma_f32_16x16x32_bf16(af[m], bfr[n],
                                                              acc[m][n], 0, 0, 0);
      __builtin_amdgcn_s_setprio(0);
    }
    cur = (cur == 2) ? 0 : cur + 1;
    nx2 = (nx2 == 2) ? 0 : nx2 + 1;
  }

  // epilogue: C/D layout col=lane&15, row=(lane>>4)*4+reg
  const int cl = lane & 15;
  const int rl4 = (lane >> 4) * 4;
#pragma unroll
  for (int n = 0; n < 4; ++n) {
    const int col = col0 + wc * 64 + n * 16 + cl;
    const float bv = bias[(size_t)e * N + col];
#pragma unroll
    for (int m = 0; m < 4; ++m) {
      const int grow = row0 + wr * 64 + m * 16 + rl4;
      CT* cp = C + (size_t)e * sCe + (size_t)grow * ldc + col;
#pragma unroll
      for (int j = 0; j < 4; ++j) {
        float v = acc[m][n][j] + bv;
        if (RELU) v = fmaxf(v, 0.f);
        if constexpr (sizeof(CT) == 2) cp[(size_t)j * ldc] = (CT)f2bf(v);
        else                           cp[(size_t)j * ldc] = (CT)v;
      }
    }
  }
}

// ------------------------- combine + task towers ---------------------------
// task_in[t] = sum_e gates[t][e] * expert_out[e]; towers 128->64(relu)->1.
__global__ __launch_bounds__(256)
void tower_kernel(const u16* __restrict__ eo,    // [8][Bc][128] bf16
                  const float* __restrict__ gates, // [Bc][2][8]
                  const float* __restrict__ tW1,   // [2][128][64]
                  const float* __restrict__ tb1, const float* __restrict__ tW2,
                  const float* __restrict__ tb2, float* __restrict__ out,
                  int rowBase, int Bc)
{
  __shared__ u16 w1s[2 * 128 * 64];
  __shared__ float tin[4][2][128];
  for (int i = threadIdx.x; i < 2 * 128 * 64; i += 256) w1s[i] = f2bf(tW1[i]);
  __syncthreads();
  const int wid = threadIdx.x >> 6, lane = threadIdx.x & 63;
  const int stride = gridDim.x * 4;
  for (int it = 0; it < 4; ++it) {
    const int r = blockIdx.x * 4 + wid + it * stride;
    const float* gp = gates + (size_t)r * 16;
    float g[16];
#pragma unroll
    for (int i = 0; i < 16; ++i) g[i] = gp[i];
    float t0a = 0.f, t0b = 0.f, t1a = 0.f, t1b = 0.f;
#pragma unroll
    for (int ee = 0; ee < 8; ++ee) {
      const u32 pv = *(const u32*)(eo + ((size_t)ee * Bc + r) * 128 + lane * 2);
      const float a = bf2f((u16)(pv & 0xffff));
      const float b = bf2f((u16)(pv >> 16));
      t0a += g[ee] * a;      t0b += g[ee] * b;
      t1a += g[8 + ee] * a;  t1b += g[8 + ee] * b;
    }
    tin[wid][0][lane * 2] = t0a; tin[wid][0][lane * 2 + 1] = t0b;
    tin[wid][1][lane * 2] = t1a; tin[wid][1][lane * 2 + 1] = t1b;
    asm volatile("s_waitcnt lgkmcnt(0)" ::: "memory");
#pragma unroll
    for (int t = 0; t < 2; ++t) {
      float acc = tb1[t * 64 + lane];
#pragma unroll 8
      for (int d = 0; d < 128; ++d)
        acc += tin[wid][t][d] * bf2f(w1s[(t * 128 + d) * 64 + lane]);
      acc = fmaxf(acc, 0.f);
      float s = acc * tW2[t * 64 + lane];
#pragma unroll
      for (int dd = 1; dd < 64; dd <<= 1) s += __shfl_xor(s, dd);
      if (lane == 0) out[(size_t)(rowBase + r) * 2 + t] = s + tb2[t];
    }
    asm volatile("s_waitcnt lgkmcnt(0)" ::: "memory");
  }
}

// ------------------------------ launch -------------------------------------
extern "C" void kernel_launch(void* const* d_in, const int* in_sizes, int n_in,
                              void* d_out, int out_size, void* d_ws, size_t ws_size,
                              hipStream_t stream) {
  const int*   X_dis   = (const int*)  d_in[0];
  const float* X_cont  = (const float*)d_in[1];
  const float* lin_emb = (const float*)d_in[2];
  const float* deep_emb= (const float*)d_in[3];
  const float* eW1     = (const float*)d_in[4];
  const float* eb1     = (const float*)d_in[5];
  const float* eW2     = (const float*)d_in[6];
  const float* eb2     = (const float*)d_in[7];
  const float* eW3     = (const float*)d_in[8];
  const float* eb3     = (const float*)d_in[9];
  const float* gW      = (const float*)d_in[10];
  const float* gb      = (const float*)d_in[11];
  const float* tW1     = (const float*)d_in[12];
  const float* tb1     = (const float*)d_in[13];
  const float* tW2     = (const float*)d_in[14];
  const float* tb2     = (const float*)d_in[15];
  float* out = (float*)d_out;

  char* ws = (char*)d_ws;
  u16* w1t = (u16*)(ws + 0);          // 8 x 512 x 704 x 2B
  u16* w2t = (u16*)(ws + 5767168);    // 8 x 256 x 512 x 2B
  u16* w3t = (u16*)(ws + 7864320);    // 8 x 128 x 256 x 2B
  const size_t base = 8388608;

  const int B = 16384;
  int NC = 1;   // per-row: ein 1408 + gates 64 + h1 8192 + h2 4096 = 13760 B
  while (NC < 64 && base + (size_t)(B / NC) * 13760ull > ws_size) NC <<= 1;
  const int Bc = B / NC;

  u16*   ein   = (u16*)  (ws + base);
  float* gates = (float*)(ws + base + (size_t)Bc * 1408);
  u16*   h1    = (u16*)  (ws + base + (size_t)Bc * 1472);
  u16*   h2    = (u16*)  (ws + base + (size_t)Bc * 1472 + (size_t)Bc * 8192);
  u16*   eo    = h1;                  // aliases h1 (dead after GEMM2)

  transpose_w_kernel<<<dim3(44, 8, 8), 256, 0, stream>>>(eW1, w1t, 650, 512, 704);
  transpose_w_kernel<<<dim3(32, 4, 8), 256, 0, stream>>>(eW2, w2t, 512, 256, 512);
  transpose_w_kernel<<<dim3(16, 2, 8), 256, 0, stream>>>(eW3, w3t, 256, 128, 256);

  for (int c = 0; c < NC; ++c) {
    const int rowBase = c * Bc;
    gather_kernel<<<Bc / 4, 256, 0, stream>>>(X_dis, X_cont, lin_emb, deep_emb,
                                              gW, gb, ein, gates, rowBase, Bc);
    gemm_kernel<true,  u16><<<dim3(4, Bc / 256, 8), 512, 0, stream>>>(
        ein, 0,                 w1t, (size_t)512 * 704,
        h1, (size_t)Bc * 512, 512, eb1, 512, 704);
    gemm_kernel<true,  u16><<<dim3(2, Bc / 256, 8), 512, 0, stream>>>(
        h1, (size_t)Bc * 512,   w2t, (size_t)256 * 512,
        h2, (size_t)Bc * 256, 256, eb2, 256, 512);
    gemm_kernel<false, u16><<<dim3(1, Bc / 256, 8), 512, 0, stream>>>(
        h2, (size_t)Bc * 256,   w3t, (size_t)128 * 256,
        eo, (size_t)Bc * 128, 128, eb3, 128, 256);
    tower_kernel<<<Bc / 16, 256, 0, stream>>>(eo, gates, tW1, tb1, tW2, tb2,
                                              out, rowBase, Bc);
  }
}

// Round 3
// 267.357 us; speedup vs baseline: 1.2789x; 1.2789x over previous
//
#include <hip/hip_runtime.h>

// ---------------------------------------------------------------------------
// MMoE forward, MI355X/gfx950.  Round 3.
// GEMM: back to the R1 structure (128x128 tile, BK=64, 4 waves, 64KB LDS,
// double-buffer, 2 blocks/CU) — R2's coarse tri-buffer at 1 block/CU was a
// measured regression (m196 pattern).  NEW: bijective XCD-aware 1-D grid
// swizzle — each XCD owns one expert; within an expert M-tile-major with
// col-tiles innermost, so blocks sharing an A-panel are co-resident and each
// expert's weights are L2-resident per XCD.  Targets the 366MB L2-miss
// traffic (unique data: 29MB) and the vmcnt(0) drain latency behind it.
// ---------------------------------------------------------------------------

typedef unsigned short u16;
typedef unsigned int u32;
typedef __attribute__((ext_vector_type(8))) __bf16 bf16x8;
typedef __attribute__((ext_vector_type(4))) float f32x4;
typedef __attribute__((ext_vector_type(4))) unsigned short u16x4;

#define DEVINL __device__ __forceinline__

DEVINL u16 f2bf(float f) {            // float -> bf16 bits, round-nearest-even
  union { float f; u32 u; } x; x.f = f;
  u32 u = x.u;
  return (u16)((u + 0x7fffu + ((u >> 16) & 1u)) >> 16);
}
DEVINL float bf2f(u16 h) {
  union { u32 u; float f; } x; x.u = ((u32)h) << 16;
  return x.f;
}
DEVINL void gload16(const u16* g, u16* l) {   // 16B global -> LDS direct
  __builtin_amdgcn_global_load_lds((const __attribute__((address_space(1))) void*)g,
                                   (__attribute__((address_space(3))) void*)l,
                                   16, 0, 0);
}

// --------------------------- weight transpose ------------------------------
// W [E][K][N] f32 -> WT [E][N][Kpad] bf16, zero-padding K..Kpad.
__global__ __launch_bounds__(256)
void transpose_w_kernel(const float* __restrict__ W, u16* __restrict__ WT,
                        int K, int N, int Kpad)
{
  __shared__ float tbuf[16][65];
  const int e = blockIdx.z;
  const float* We = W + (size_t)e * K * N;
  u16* Wt = WT + (size_t)e * N * Kpad;
  const int k0 = blockIdx.x * 16, n0 = blockIdx.y * 64;
#pragma unroll
  for (int p = 0; p < 4; ++p) {
    const int idx = threadIdx.x + p * 256;
    const int nl = idx & 63, kl = idx >> 6;
    const int gk = k0 + kl;
    tbuf[kl][nl] = (gk < K) ? We[(size_t)gk * N + n0 + nl] : 0.f;
  }
  __syncthreads();
#pragma unroll
  for (int p = 0; p < 4; ++p) {
    const int idx = threadIdx.x + p * 256;
    const int kl = idx & 15, nl = idx >> 4;
    Wt[(size_t)(n0 + nl) * Kpad + k0 + kl] = f2bf(tbuf[kl][nl]);
  }
}

// ------------------------------- gather ------------------------------------
// One wave per row: bf16 expert_in[row][704] (deep 640 | cont 10 | pad 54),
// fp32 softmax gates[row][2][8].  Deep gather uses float4 (16B) loads.
__global__ __launch_bounds__(256)
void gather_kernel(const int* __restrict__ Xd, const float* __restrict__ Xc,
                   const float* __restrict__ lin_emb, const float* __restrict__ deep_emb,
                   const float* __restrict__ gW, const float* __restrict__ gb,
                   u16* __restrict__ ein, float* __restrict__ gates,
                   int rowBase, int Bc)
{
  __shared__ float gi[4][32];
  const int wid = threadIdx.x >> 6, lane = threadIdx.x & 63;
  const int rl = blockIdx.x * 4 + wid;
  const int r = rowBase + rl;
  const int* xd = Xd + (size_t)r * 20;
  u16* er = ein + (size_t)rl * 704;
#pragma unroll
  for (int i = 0; i < 3; ++i) {                 // 20 feat x 8 subchunks = 160
    const int li = i * 64 + lane;
    if (li < 160) {
      const int f = li >> 3, sub = li & 7;
      const int idx = xd[f];
      const float4 v = *(const float4*)&deep_emb[((size_t)f * 100000 + idx) * 32 + sub * 4];
      u16x4 o;
      o.x = f2bf(v.x); o.y = f2bf(v.y); o.z = f2bf(v.z); o.w = f2bf(v.w);
      *(u16x4*)&er[f * 32 + sub * 4] = o;
    }
  }
  if (lane < 10) er[640 + lane] = f2bf(Xc[(size_t)r * 10 + lane]);
  if (lane < 54) er[650 + lane] = 0;
  if (lane < 20) gi[wid][lane] = lin_emb[(size_t)lane * 100000 + xd[lane]];
  if (lane < 10) gi[wid][20 + lane] = Xc[(size_t)r * 10 + lane];
  asm volatile("s_waitcnt lgkmcnt(0)" ::: "memory");
  float logit = 0.f;
  const int t = lane >> 3, ee = lane & 7;
  if (lane < 16) {
    float a = gb[t * 8 + ee];
#pragma unroll
    for (int i = 0; i < 30; ++i) a += gi[wid][i] * gW[(t * 30 + i) * 8 + ee];
    logit = a;
  }
  float mx = logit;
#pragma unroll
  for (int d = 1; d < 8; d <<= 1) mx = fmaxf(mx, __shfl_xor(mx, d));
  float p = expf(logit - mx);
  float sm = p;
#pragma unroll
  for (int d = 1; d < 8; d <<= 1) sm += __shfl_xor(sm, d);
  if (lane < 16) gates[(size_t)rl * 16 + lane] = p / sm;
}

// ------------------------------ grouped GEMM -------------------------------
// C[e] = act(A[e] [M x K] * B[e]^T [N x K] + bias[e]);  K mult of 64, M mult
// of 128, N mult of 128.  1-D grid nCol*nRow*8, block 256 (4 waves, 64x64).
// Work decode: XCD x (the hardware round-robins consecutive blockIdx across
// XCDs) owns a contiguous work chunk = one expert; within an expert M-tile
// major, col-tile innermost (A-panel sharers time-adjacent).
template<bool RELU, typename CT>
__global__ __launch_bounds__(256, 2)
void gemm_kernel(const u16* __restrict__ A, size_t sAe,
                 const u16* __restrict__ Bw, size_t sBe,
                 CT* __restrict__ C, size_t sCe, int ldc,
                 const float* __restrict__ bias, int N, int K,
                 int nCol, int nRow)
{
  __shared__ u16 As[2][8192];   // [128][64] bf16, XOR-swizzled via source
  __shared__ u16 Bs[2][8192];

  const int perE = nCol * nRow;
  const int work = (blockIdx.x & 7) * perE + (blockIdx.x >> 3); // chunk/XCD
  const int e  = work / perE;
  const int rem = work - e * perE;
  const int mt = rem / nCol;
  const int ct = rem - mt * nCol;

  const u16* Ae = A + (size_t)e * sAe;
  const u16* Be = Bw + (size_t)e * sBe;
  const int row0 = mt * 128;
  const int col0 = ct * 128;
  const int tid = threadIdx.x;
  const int lane = tid & 63;
  const int wid = tid >> 6;
  const int wr = wid >> 1, wc = wid & 1;         // wave -> 64x64 quadrant

  // Staging: LDS dest linear (wave-uniform base + lane*16B); XOR swizzle is
  // applied to the GLOBAL source chunk (ch ^ (row&7)); ds_read applies the
  // same involution.
  int rw_[4], gch_[4], ldsOff_[4];
#pragma unroll
  for (int i = 0; i < 4; ++i) {
    const int o = (wid * 4 + i) * 1024 + lane * 16;   // byte off in 16KB tile
    rw_[i] = o >> 7;                                  // row 0..127
    const int ch = (o >> 4) & 7;
    gch_[i] = ch ^ (rw_[i] & 7);
    ldsOff_[i] = (wid * 4 + i) * 512;                 // u16 units
  }
  const int KT = K >> 6;

  auto stage = [&](int buf, int kt) {
    const int kb = kt << 6;
#pragma unroll
    for (int i = 0; i < 4; ++i) {
      gload16(Ae + ((size_t)(row0 + rw_[i]) * K + kb + (gch_[i] << 3)),
              &As[buf][ldsOff_[i]]);
      gload16(Be + ((size_t)(col0 + rw_[i]) * K + kb + (gch_[i] << 3)),
              &Bs[buf][ldsOff_[i]]);
    }
  };

  f32x4 acc[4][4];
#pragma unroll
  for (int m = 0; m < 4; ++m)
#pragma unroll
    for (int n = 0; n < 4; ++n) acc[m][n] = {0.f, 0.f, 0.f, 0.f};

  stage(0, 0);
  __syncthreads();                               // drains vmcnt(0) too

  for (int kt = 0; kt < KT; ++kt) {
    const int cur = kt & 1;
    if (kt + 1 < KT) stage(cur ^ 1, kt + 1);     // prefetch in flight over MFMA
#pragma unroll
    for (int half = 0; half < 2; ++half) {       // k = 0..31, 32..63
      const int kp = half * 4 + (lane >> 4);
      bf16x8 af[4], bfr[4];
#pragma unroll
      for (int m = 0; m < 4; ++m) {
        const int rw = wr * 64 + m * 16 + (lane & 15);
        af[m] = *(const bf16x8*)&As[cur][rw * 64 + ((kp ^ (rw & 7)) << 3)];
      }
#pragma unroll
      for (int n = 0; n < 4; ++n) {
        const int rw = wc * 64 + n * 16 + (lane & 15);
        bfr[n] = *(const bf16x8*)&Bs[cur][rw * 64 + ((kp ^ (rw & 7)) << 3)];
      }
      __builtin_amdgcn_s_setprio(1);
#pragma unroll
      for (int m = 0; m < 4; ++m)
#pragma unroll
        for (int n = 0; n < 4; ++n)
          acc[m][n] = __builtin_amdgcn_mfma_f32_16x16x32_bf16(af[m], bfr[n],
                                                              acc[m][n], 0, 0, 0);
      __builtin_amdgcn_s_setprio(0);
    }
    __syncthreads();   // next-tile staging complete + all reads of cur done
  }

  // epilogue: C/D layout col=lane&15, row=(lane>>4)*4+reg
  const int cl = lane & 15;
  const int rl4 = (lane >> 4) * 4;
#pragma unroll
  for (int n = 0; n < 4; ++n) {
    const int col = col0 + wc * 64 + n * 16 + cl;
    const float bv = bias[(size_t)e * N + col];
#pragma unroll
    for (int m = 0; m < 4; ++m) {
      const int grow = row0 + wr * 64 + m * 16 + rl4;
      CT* cp = C + (size_t)e * sCe + (size_t)grow * ldc + col;
#pragma unroll
      for (int j = 0; j < 4; ++j) {
        float v = acc[m][n][j] + bv;
        if (RELU) v = fmaxf(v, 0.f);
        if constexpr (sizeof(CT) == 2) cp[(size_t)j * ldc] = (CT)f2bf(v);
        else                           cp[(size_t)j * ldc] = (CT)v;
      }
    }
  }
}

// ------------------------- combine + task towers ---------------------------
__global__ __launch_bounds__(256)
void tower_kernel(const u16* __restrict__ eo,      // [8][Bc][128] bf16
                  const float* __restrict__ gates, // [Bc][2][8]
                  const float* __restrict__ tW1,   // [2][128][64]
                  const float* __restrict__ tb1, const float* __restrict__ tW2,
                  const float* __restrict__ tb2, float* __restrict__ out,
                  int rowBase, int Bc)
{
  __shared__ u16 w1s[2 * 128 * 64];
  __shared__ float tin[4][2][128];
  for (int i = threadIdx.x; i < 2 * 128 * 64; i += 256) w1s[i] = f2bf(tW1[i]);
  __syncthreads();
  const int wid = threadIdx.x >> 6, lane = threadIdx.x & 63;
  const int stride = gridDim.x * 4;
  for (int it = 0; it < 4; ++it) {
    const int r = blockIdx.x * 4 + wid + it * stride;
    const float* gp = gates + (size_t)r * 16;
    float g[16];
#pragma unroll
    for (int i = 0; i < 16; ++i) g[i] = gp[i];
    float t0a = 0.f, t0b = 0.f, t1a = 0.f, t1b = 0.f;
#pragma unroll
    for (int ee = 0; ee < 8; ++ee) {
      const u32 pv = *(const u32*)(eo + ((size_t)ee * Bc + r) * 128 + lane * 2);
      const float a = bf2f((u16)(pv & 0xffff));
      const float b = bf2f((u16)(pv >> 16));
      t0a += g[ee] * a;      t0b += g[ee] * b;
      t1a += g[8 + ee] * a;  t1b += g[8 + ee] * b;
    }
    tin[wid][0][lane * 2] = t0a; tin[wid][0][lane * 2 + 1] = t0b;
    tin[wid][1][lane * 2] = t1a; tin[wid][1][lane * 2 + 1] = t1b;
    asm volatile("s_waitcnt lgkmcnt(0)" ::: "memory");
#pragma unroll
    for (int t = 0; t < 2; ++t) {
      float acc = tb1[t * 64 + lane];
#pragma unroll 8
      for (int d = 0; d < 128; ++d)
        acc += tin[wid][t][d] * bf2f(w1s[(t * 128 + d) * 64 + lane]);
      acc = fmaxf(acc, 0.f);
      float s = acc * tW2[t * 64 + lane];
#pragma unroll
      for (int dd = 1; dd < 64; dd <<= 1) s += __shfl_xor(s, dd);
      if (lane == 0) out[(size_t)(rowBase + r) * 2 + t] = s + tb2[t];
    }
    asm volatile("s_waitcnt lgkmcnt(0)" ::: "memory");
  }
}

// ------------------------------ launch -------------------------------------
extern "C" void kernel_launch(void* const* d_in, const int* in_sizes, int n_in,
                              void* d_out, int out_size, void* d_ws, size_t ws_size,
                              hipStream_t stream) {
  const int*   X_dis   = (const int*)  d_in[0];
  const float* X_cont  = (const float*)d_in[1];
  const float* lin_emb = (const float*)d_in[2];
  const float* deep_emb= (const float*)d_in[3];
  const float* eW1     = (const float*)d_in[4];
  const float* eb1     = (const float*)d_in[5];
  const float* eW2     = (const float*)d_in[6];
  const float* eb2     = (const float*)d_in[7];
  const float* eW3     = (const float*)d_in[8];
  const float* eb3     = (const float*)d_in[9];
  const float* gW      = (const float*)d_in[10];
  const float* gb      = (const float*)d_in[11];
  const float* tW1     = (const float*)d_in[12];
  const float* tb1     = (const float*)d_in[13];
  const float* tW2     = (const float*)d_in[14];
  const float* tb2     = (const float*)d_in[15];
  float* out = (float*)d_out;

  char* ws = (char*)d_ws;
  u16* w1t = (u16*)(ws + 0);          // 8 x 512 x 704 x 2B
  u16* w2t = (u16*)(ws + 5767168);    // 8 x 256 x 512 x 2B
  u16* w3t = (u16*)(ws + 7864320);    // 8 x 128 x 256 x 2B
  const size_t base = 8388608;

  const int B = 16384;
  int NC = 1;   // per-row: ein 1408 + gates 64 + h1 8192 + h2 4096 = 13760 B
  while (NC < 64 && base + (size_t)(B / NC) * 13760ull > ws_size) NC <<= 1;
  const int Bc = B / NC;

  u16*   ein   = (u16*)  (ws + base);
  float* gates = (float*)(ws + base + (size_t)Bc * 1408);
  u16*   h1    = (u16*)  (ws + base + (size_t)Bc * 1472);
  u16*   h2    = (u16*)  (ws + base + (size_t)Bc * 1472 + (size_t)Bc * 8192);
  u16*   eo    = h1;                  // aliases h1 (dead after GEMM2)

  transpose_w_kernel<<<dim3(44, 8, 8), 256, 0, stream>>>(eW1, w1t, 650, 512, 704);
  transpose_w_kernel<<<dim3(32, 4, 8), 256, 0, stream>>>(eW2, w2t, 512, 256, 512);
  transpose_w_kernel<<<dim3(16, 2, 8), 256, 0, stream>>>(eW3, w3t, 256, 128, 256);

  for (int c = 0; c < NC; ++c) {
    const int rowBase = c * Bc;
    const int nRow = Bc / 128;
    gather_kernel<<<Bc / 4, 256, 0, stream>>>(X_dis, X_cont, lin_emb, deep_emb,
                                              gW, gb, ein, gates, rowBase, Bc);
    gemm_kernel<true,  u16><<<4 * nRow * 8, 256, 0, stream>>>(
        ein, 0,                 w1t, (size_t)512 * 704,
        h1, (size_t)Bc * 512, 512, eb1, 512, 704, 4, nRow);
    gemm_kernel<true,  u16><<<2 * nRow * 8, 256, 0, stream>>>(
        h1, (size_t)Bc * 512,   w2t, (size_t)256 * 512,
        h2, (size_t)Bc * 256, 256, eb2, 256, 512, 2, nRow);
    gemm_kernel<false, u16><<<1 * nRow * 8, 256, 0, stream>>>(
        h2, (size_t)Bc * 256,   w3t, (size_t)128 * 256,
        eo, (size_t)Bc * 128, 128, eb3, 128, 256, 1, nRow);
    tower_kernel<<<Bc / 16, 256, 0, stream>>>(eo, gates, tW1, tb1, tW2, tb2,
                                              out, rowBase, Bc);
  }
}